// Round 7
// baseline (270.789 us; speedup 1.0000x reference)
//
#include <hip/hip_runtime.h>
#include <math.h>

// EnergySRB, R12: kill the contended global-atomic drain.
// R10 ablations (none of which included the epilogue) summed to 94.5us vs
// the 84us full kernel; R5-R11 invariance to occupancy/schedule/cache-state
// plus WRITE_SIZE = 16MB = 2.1M x 8B pointed at the one shared, never-
// ablated component: 512 blocks x 4096 contended device-scope u64 atomics,
// executed write-through at the memory side (per-XCD L2s aren't coherent),
// ~512 serialized RMWs per address ~= 40-60us every dispatch must drain.
// R12: each block stores its bins NON-atomically to part[block][4096]
// (16KB coalesced stores; 8MB total), then a 2-level reduce: 128 blocks
// sum 64 rows each -> 8 u64 atomics/mol (negligible contention) -> existing
// final_kernel. Integer sums -> bit-identical output. Loop = proven simple
// gen loop; LDS exactly 80KB (2 blocks/CU) kept.

#define NT        1024
#define NBLK      512
#define SCALE_F   134217728.0f              // 2^27
#define INV_SCALE 7.450580596923828125e-9   // 2^-27, exact in double

// ---------------------------------------------------------------------------
// pack species (values 0..3) into 2-bit words. 262144 atoms -> 64KB.
__global__ void pack_species_kernel(const int* __restrict__ sp,
                                    unsigned* __restrict__ packed, int nwords) {
    int w = blockIdx.x * blockDim.x + threadIdx.x;
    if (w >= nwords) return;
    const int4* p4 = (const int4*)(sp + (w << 4));
    int4 a = p4[0], b = p4[1], c = p4[2], d = p4[3];
    unsigned v =
        (unsigned)(a.x & 3)        | ((unsigned)(a.y & 3) << 2)  |
        ((unsigned)(a.z & 3) << 4) | ((unsigned)(a.w & 3) << 6)  |
        ((unsigned)(b.x & 3) << 8) | ((unsigned)(b.y & 3) << 10) |
        ((unsigned)(b.z & 3) << 12)| ((unsigned)(b.w & 3) << 14) |
        ((unsigned)(c.x & 3) << 16)| ((unsigned)(c.y & 3) << 18) |
        ((unsigned)(c.z & 3) << 20)| ((unsigned)(c.w & 3) << 22) |
        ((unsigned)(d.x & 3) << 24)| ((unsigned)(d.y & 3) << 26) |
        ((unsigned)(d.z & 3) << 28)| ((unsigned)(d.w & 3) << 30);
    packed[w] = v;
}

// ---------------------------------------------------------------------------
// init: species passthrough; zero the u64 accumulator.
__global__ void init_kernel(const int* __restrict__ species,
                            float* __restrict__ out,
                            unsigned long long* __restrict__ acc,
                            int n_species, int n_mol) {
    int i = blockIdx.x * blockDim.x + threadIdx.x;
    if (i < n_species) out[i] = (float)species[i];
    if (i < n_mol)     acc[i] = 0ull;
}

// ---------------------------------------------------------------------------
// Main fused kernel: LDS 80KB (64KB packed species + 16KB u32 bins) ->
// 2 blocks/CU. Epilogue: PLAIN coalesced stores to part[bid*4096..] -
// no global atomics.
__global__ __launch_bounds__(NT, 8)
void srb_fused_u32_part(const unsigned* __restrict__ packed_ws,
                        const int* __restrict__ ai,     // [2, P]
                        const float* __restrict__ dist, // [P] angstrom
                        const float* __restrict__ pre_tab,   // 16 floats (neg)
                        const float* __restrict__ dfac_tab,  // 16 floats
                        unsigned* __restrict__ part,    // [gridDim.x * 4096]
                        int P, int mol_shift) {
    __shared__ unsigned packed[16384]; // 64KB
    __shared__ unsigned binsu[4096];   // 16KB (total exactly 80KB)

    const int t = threadIdx.x;
    for (int i = t; i < 4096; i += NT) binsu[i] = 0u;

    // register-resident table: lane L of each wave holds entry L&15.
    const float myPre  = -pre_tab[t & 15];   // magnitude, > 0
    const float myDfac =  dfac_tab[t & 15];

    {
        int4* dst = (int4*)packed;
        const int4* src = (const int4*)packed_ws;
        for (int i = t; i < 4096; i += NT) dst[i] = src[i];
    }
    __syncthreads();

    const float a2b   = (float)1.8897261258369282;
    const float rc    = (float)(5.2 * 1.8897261258369282);
    const float rcinv = (float)(1.0 / (5.2 * 1.8897261258369282));

    const int ng     = P >> 2;                 // groups of 4
    const int stride = (int)gridDim.x * NT;
    const int4*   v0 = (const int4*)ai;
    const int4*   v1 = (const int4*)(ai + P);
    const float4* dv = (const float4*)dist;

    for (int g = (int)blockIdx.x * NT + t; g < ng; g += stride) {
        int4 I0 = v0[g], I1 = v1[g]; float4 D = dv[g];
        unsigned a0[4] = { (unsigned)I0.x, (unsigned)I0.y,
                           (unsigned)I0.z, (unsigned)I0.w };
        unsigned a1[4] = { (unsigned)I1.x, (unsigned)I1.y,
                           (unsigned)I1.z, (unsigned)I1.w };
        float    dd[4] = { D.x, D.y, D.z, D.w };

        // Phase 1: all 8 species gathers in flight.
        unsigned w0[4], w1[4];
        #pragma unroll
        for (int k = 0; k < 4; ++k) w0[k] = packed[a0[k] >> 4];
        #pragma unroll
        for (int k = 0; k < 4; ++k) w1[k] = packed[a1[k] >> 4];

        // Phase 2: table lookup via wave shuffle (ds_bpermute).
        float pr[4], df[4];
        #pragma unroll
        for (int k = 0; k < 4; ++k) {
            unsigned s0 = (w0[k] >> ((a0[k] & 15u) << 1)) & 3u;
            unsigned s1 = (w1[k] >> ((a1[k] & 15u) << 1)) & 3u;
            int idx = (int)((s0 << 2) | s1);
            pr[k] = __shfl(myPre,  idx, 64);
            df[k] = __shfl(myDfac, idx, 64);
        }

        // Phase 3: 4 independent VALU chains (bit-identical to R5-R11).
        unsigned q[4];
        #pragma unroll
        for (int k = 0; k < 4; ++k) {
            float db  = dd[k] * a2b;
            float x   = db * rcinv;
            float arg = df[k] * db + (1.0f - 1.0f / (1.0f - x * x));
            float mag = pr[k] * __expf(arg);     // pr = |pre| > 0
            mag = (db < rc) ? mag : 0.0f;        // exact 0 beyond cutoff
            q[k] = (unsigned)(mag * SCALE_F);    // trunc; < 2^24 always
        }

        // Phase 4: 4 LDS atomics (native ds_add_u32).
        #pragma unroll
        for (int k = 0; k < 4; ++k)
            atomicAdd(&binsu[a0[k] >> mol_shift], q[k]);
    }

    __syncthreads();
    // Epilogue: plain coalesced stores - NO global atomics.
    unsigned* dst = part + (size_t)blockIdx.x * 4096;
    for (int i = t; i < 4096; i += NT) dst[i] = binsu[i];
}

// ---------------------------------------------------------------------------
// Level-1 reduce: grid (ceil(n_mol/256), 8); each block sums nblk/8 rows
// for 256 mols, one u64 atomic per mol (8 per address total).
__global__ void reduce_partial(const unsigned* __restrict__ part,
                               unsigned long long* __restrict__ acc,
                               int n_mol, int nblk) {
    int m = blockIdx.x * blockDim.x + threadIdx.x;
    if (m >= n_mol) return;
    const int nb8 = (nblk + 7) >> 3;
    int b0 = blockIdx.y * nb8;
    int b1 = b0 + nb8; if (b1 > nblk) b1 = nblk;
    unsigned long long s = 0;
    for (int b = b0; b < b1; ++b)
        s += part[(size_t)b * 4096 + m];       // coalesced across threads
    if (s) atomicAdd(&acc[m], s);
}

// ---------------------------------------------------------------------------
// final: out_e[m] = energies[m] - acc[m] * 2^-27  (exact in double)
__global__ void final_kernel(const unsigned long long* __restrict__ acc,
                             const float* __restrict__ energies,
                             float* __restrict__ out_e, int n_mol) {
    int m = blockIdx.x * blockDim.x + threadIdx.x;
    if (m < n_mol)
        out_e[m] = energies[m] - (float)((double)acc[m] * INV_SCALE);
}

// ---------------------------------------------------------------------------
// Middle path (ws too small for partials): R6-lineage u64-atomic drain.
__global__ __launch_bounds__(NT, 8)
void srb_fused_u32_gen(const unsigned* __restrict__ packed_ws,
                       const int* __restrict__ ai,
                       const float* __restrict__ dist,
                       const float* __restrict__ pre_tab,
                       const float* __restrict__ dfac_tab,
                       unsigned long long* __restrict__ acc,
                       int P, int mol_shift) {
    __shared__ unsigned packed[16384];
    __shared__ unsigned binsu[4096];

    const int t = threadIdx.x;
    for (int i = t; i < 4096; i += NT) binsu[i] = 0u;
    const float myPre  = -pre_tab[t & 15];
    const float myDfac =  dfac_tab[t & 15];
    {
        int4* dst = (int4*)packed;
        const int4* src = (const int4*)packed_ws;
        for (int i = t; i < 4096; i += NT) dst[i] = src[i];
    }
    __syncthreads();

    const float a2b   = (float)1.8897261258369282;
    const float rc    = (float)(5.2 * 1.8897261258369282);
    const float rcinv = (float)(1.0 / (5.2 * 1.8897261258369282));

    const int ng     = P >> 2;
    const int stride = (int)gridDim.x * NT;
    const int4*   v0 = (const int4*)ai;
    const int4*   v1 = (const int4*)(ai + P);
    const float4* dv = (const float4*)dist;

    for (int g = (int)blockIdx.x * NT + t; g < ng; g += stride) {
        int4 I0 = v0[g], I1 = v1[g]; float4 D = dv[g];
        unsigned a0[4] = { (unsigned)I0.x, (unsigned)I0.y,
                           (unsigned)I0.z, (unsigned)I0.w };
        unsigned a1[4] = { (unsigned)I1.x, (unsigned)I1.y,
                           (unsigned)I1.z, (unsigned)I1.w };
        float    dd[4] = { D.x, D.y, D.z, D.w };
        unsigned w0[4], w1[4];
        #pragma unroll
        for (int k = 0; k < 4; ++k) w0[k] = packed[a0[k] >> 4];
        #pragma unroll
        for (int k = 0; k < 4; ++k) w1[k] = packed[a1[k] >> 4];
        float pr[4], df[4];
        #pragma unroll
        for (int k = 0; k < 4; ++k) {
            unsigned s0 = (w0[k] >> ((a0[k] & 15u) << 1)) & 3u;
            unsigned s1 = (w1[k] >> ((a1[k] & 15u) << 1)) & 3u;
            int idx = (int)((s0 << 2) | s1);
            pr[k] = __shfl(myPre,  idx, 64);
            df[k] = __shfl(myDfac, idx, 64);
        }
        unsigned q[4];
        #pragma unroll
        for (int k = 0; k < 4; ++k) {
            float db  = dd[k] * a2b;
            float x   = db * rcinv;
            float arg = df[k] * db + (1.0f - 1.0f / (1.0f - x * x));
            float mag = pr[k] * __expf(arg);
            mag = (db < rc) ? mag : 0.0f;
            q[k] = (unsigned)(mag * SCALE_F);
        }
        #pragma unroll
        for (int k = 0; k < 4; ++k)
            atomicAdd(&binsu[a0[k] >> mol_shift], q[k]);
    }

    __syncthreads();
    for (int i = t; i < 4096; i += NT) {
        unsigned v = binsu[i];
        if (v) atomicAdd(&acc[i], (unsigned long long)v);
    }
}

// ---------------------------------------------------------------------------
// Fallback (ws tiny): fused float-atomic path, out_e preset.
__global__ void init_out_fallback(const int* __restrict__ species,
                                  const float* __restrict__ energies,
                                  float* __restrict__ out,
                                  int n_species, int n_mol) {
    int i = blockIdx.x * blockDim.x + threadIdx.x;
    if (i < n_species) out[i] = (float)species[i];
    else if (i < n_species + n_mol) out[i] = energies[i - n_species];
}

__global__ __launch_bounds__(NT, 1)
void srb_fused_f32(const int* __restrict__ species,
                   const int* __restrict__ ai,
                   const float* __restrict__ dist,
                   const float* __restrict__ pre_tab,
                   const float* __restrict__ dfac_tab,
                   float* __restrict__ out_e,
                   int P, int mol_shift) {
    __shared__ unsigned packed[16384];
    __shared__ float bins[4096];
    __shared__ float2 tab[16];
    const int t = threadIdx.x;
    for (int i = t; i < 4096; i += NT) bins[i] = 0.0f;
    if (t < 16) tab[t] = make_float2(pre_tab[t], dfac_tab[t]);
    for (int w = t; w < 16384; w += NT) {
        const int4* p4 = (const int4*)(species + (w << 4));
        int4 a = p4[0], b = p4[1], c = p4[2], d = p4[3];
        unsigned v =
            (unsigned)(a.x & 3)        | ((unsigned)(a.y & 3) << 2)  |
            ((unsigned)(a.z & 3) << 4) | ((unsigned)(a.w & 3) << 6)  |
            ((unsigned)(b.x & 3) << 8) | ((unsigned)(b.y & 3) << 10) |
            ((unsigned)(b.z & 3) << 12)| ((unsigned)(b.w & 3) << 14) |
            ((unsigned)(c.x & 3) << 16)| ((unsigned)(c.y & 3) << 18) |
            ((unsigned)(c.z & 3) << 20)| ((unsigned)(c.w & 3) << 22) |
            ((unsigned)(d.x & 3) << 24)| ((unsigned)(d.y & 3) << 26) |
            ((unsigned)(d.z & 3) << 28)| ((unsigned)(d.w & 3) << 30);
        packed[w] = v;
    }
    __syncthreads();
    const float a2b   = (float)1.8897261258369282;
    const float rc    = (float)(5.2 * 1.8897261258369282);
    const float rcinv = (float)(1.0 / (5.2 * 1.8897261258369282));
    auto body = [&](int a0, int a1, float dang) {
        unsigned ua0 = (unsigned)a0, ua1 = (unsigned)a1;
        unsigned s0 = (packed[ua0 >> 4] >> ((ua0 & 15u) << 1)) & 3u;
        unsigned s1 = (packed[ua1 >> 4] >> ((ua1 & 15u) << 1)) & 3u;
        float2 td = tab[(s0 << 2) | s1];
        float db = dang * a2b;
        float x  = db * rcinv;
        float arg = td.y * db + (1.0f - 1.0f / (1.0f - x * x));
        float srb = td.x * __expf(arg);
        srb = (db < rc) ? srb : 0.0f;
        atomicAdd(&bins[ua0 >> mol_shift], srb);
    };
    const int nv = P >> 2, stride = (int)gridDim.x * NT;
    const int4* v0 = (const int4*)ai;
    const int4* v1 = (const int4*)(ai + P);
    const float4* dv = (const float4*)dist;
    for (int v = (int)blockIdx.x * NT + t; v < nv; v += stride) {
        int4 i0 = v0[v]; int4 i1 = v1[v]; float4 dd = dv[v];
        body(i0.x, i1.x, dd.x); body(i0.y, i1.y, dd.y);
        body(i0.z, i1.z, dd.z); body(i0.w, i1.w, dd.w);
    }
    __syncthreads();
    for (int i = t; i < 4096; i += NT) {
        float s = bins[i];
        if (s != 0.0f) atomicAdd(&out_e[i], s);
    }
}

// ---------------------------------------------------------------------------
extern "C" void kernel_launch(void* const* d_in, const int* in_sizes, int n_in,
                              void* d_out, int out_size, void* d_ws, size_t ws_size,
                              hipStream_t stream) {
    const int*   species  = (const int*)d_in[0];
    const float* energies = (const float*)d_in[1];
    const int*   ai       = (const int*)d_in[2];
    const float* dist     = (const float*)d_in[3];
    const float* pre_tab  = (const float*)d_in[4];
    const float* dfac_tab = (const float*)d_in[5];

    const int n_species = in_sizes[0];            // 262144
    const int n_mol     = in_sizes[1];            // 4096
    const int P         = in_sizes[3];            // 16777216
    const int n_atoms   = n_species / n_mol;      // 64

    int mol_shift = 0;
    while ((1 << mol_shift) < n_atoms) ++mol_shift; // 6

    float* out   = (float*)d_out;
    float* out_e = out + n_species;

    const int    nwords    = n_species / 16;              // 16384
    const size_t packed_sz = (size_t)nwords * 4;          // 64KB
    const size_t acc_sz    = (size_t)n_mol * 8;           // 32KB
    const size_t part_sz   = (size_t)NBLK * 4096 * 4;     // 8MB
    const size_t need_part = packed_sz + acc_sz + part_sz;
    const size_t need_atom = packed_sz + acc_sz;

    if (ws_size >= need_part && (P & 3) == 0) {
        // Path A: private partials + tree reduce (no contended atomics).
        unsigned*           packed = (unsigned*)d_ws;
        unsigned long long* acc    = (unsigned long long*)((char*)d_ws + packed_sz);
        unsigned*           part   = (unsigned*)((char*)d_ws + packed_sz + acc_sz);

        init_kernel<<<(n_species + 255) / 256, 256, 0, stream>>>(
            species, out, acc, n_species, n_mol);
        pack_species_kernel<<<(nwords + 255) / 256, 256, 0, stream>>>(
            species, packed, nwords);
        srb_fused_u32_part<<<NBLK, NT, 0, stream>>>(
            packed, ai, dist, pre_tab, dfac_tab, part, P, mol_shift);
        dim3 rgrid((n_mol + 255) / 256, 8);
        reduce_partial<<<rgrid, 256, 0, stream>>>(part, acc, n_mol, NBLK);
        final_kernel<<<(n_mol + 255) / 256, 256, 0, stream>>>(
            acc, energies, out_e, n_mol);
    } else if (ws_size >= need_atom && (P & 3) == 0) {
        // Path B: u64-atomic drain (previous behavior).
        unsigned*           packed = (unsigned*)d_ws;
        unsigned long long* acc    = (unsigned long long*)((char*)d_ws + packed_sz);

        init_kernel<<<(n_species + 255) / 256, 256, 0, stream>>>(
            species, out, acc, n_species, n_mol);
        pack_species_kernel<<<(nwords + 255) / 256, 256, 0, stream>>>(
            species, packed, nwords);
        srb_fused_u32_gen<<<NBLK, NT, 0, stream>>>(
            packed, ai, dist, pre_tab, dfac_tab, acc, P, mol_shift);
        final_kernel<<<(n_mol + 255) / 256, 256, 0, stream>>>(
            acc, energies, out_e, n_mol);
    } else {
        init_out_fallback<<<(n_species + n_mol + 255) / 256, 256, 0, stream>>>(
            species, energies, out, n_species, n_mol);
        srb_fused_f32<<<NBLK, NT, 0, stream>>>(
            species, ai, dist, pre_tab, dfac_tab, out_e, P, mol_shift);
    }
}